// Round 9
// baseline (153.585 us; speedup 1.0000x reference)
//
#include <hip/hip_runtime.h>
#include <math.h>

#define B_    2
#define L_    2048
#define H_    16
#define D_    128
#define S_    40
#define NTOP_ 40
#define NCH_  8        // key chunks for attention
#define CHK_  256      // keys per chunk (attention)
#define VCH_  32       // L chunks for vmean
#define CAND_ 512      // refine candidate capacity

#define SCALE_ 0.08838834764831843f  // 1/sqrt(128)

// monotone float<->uint encoding (order-preserving, incl. negatives)
__device__ __forceinline__ unsigned int encf(float f) {
    unsigned int u = __float_as_uint(f);
    return (u & 0x80000000u) ? ~u : (u | 0x80000000u);
}
__device__ __forceinline__ float decf(unsigned int e) {
    unsigned int u = (e & 0x80000000u) ? (e ^ 0x80000000u) : ~e;
    return __uint_as_float(u);
}
__device__ __forceinline__ unsigned int bfpack(float a, float b) {  // RNE bf16 pair
    unsigned int ua = __float_as_uint(a); ua = (ua + 0x7fffu + ((ua >> 16) & 1u)) >> 16;
    unsigned int ub = __float_as_uint(b); ub = (ub + 0x7fffu + ((ub >> 16) & 1u)) >> 16;
    return ua | (ub << 16);
}
__device__ __forceinline__ float lo16(unsigned int u) { return __uint_as_float(u << 16); }
__device__ __forceinline__ float hi16(unsigned int u) { return __uint_as_float(u & 0xffff0000u); }

// ---------------- kpack: K -> bf16 rows Kbf[(bh*L+ki)*128 + d] ---------------
__global__ __launch_bounds__(256) void kpack(const float* __restrict__ K,
                                             unsigned int* __restrict__ Kbf) {
    const int bid = blockIdx.x, t = threadIdx.x;   // 256 blocks = (bh, kc of 256)
    const int bh = bid >> 3, kc = bid & 7;
    const int h = bh & 15, b = bh >> 4;
    const float4* K4 = (const float4*)K;
    uint2* out2 = (uint2*)Kbf;
    for (int j = 0; j < 32; ++j) {
        const int g = j * 256 + t;                 // 0..8191
        const int row = g >> 5, c = g & 31;
        const float4 v = K4[((size_t)(b * L_ + kc * 256 + row) * H_ + h) * 32 + c];
        out2[(size_t)(bh * L_ + kc * 256 + row) * 32 + c] =
            make_uint2(bfpack(v.x, v.y), bfpack(v.z, v.w));
    }
}

// ---------------- k0: V partial sums ----------------------------------------
__global__ __launch_bounds__(256) void k0_vpart(const float* __restrict__ V,
                                                float* __restrict__ vpart) {
    __shared__ float red[256];
    const int vbid = blockIdx.x;         // bh*VCH_ + lc
    const int bh  = vbid >> 5;
    const int lc  = vbid & (VCH_ - 1);
    const int h   = bh & 15, b = bh >> 4;
    const int t   = threadIdx.x;
    const int d   = t & (D_ - 1);
    const int sub = t >> 7;
    float acc = 0.0f;
    const int l0 = lc * (L_ / VCH_);
    for (int l = l0 + sub; l < l0 + L_ / VCH_; l += 2)
        acc += V[((size_t)(b * L_ + l) * H_ + h) * D_ + d];
    red[t] = acc;
    __syncthreads();
    if (t < D_) vpart[(size_t)vbid * D_ + t] = red[t] + red[t + 128];
}

// ---------------- k1 (bf16): sampled approx M --------------------------------
// One wave per q-row; 8 lanes span D (16B bf16 = 8 dims per lane per half).
// 2 cache lines per (q,s) pair instead of 4. XCD-pinned bh slices.
__global__ __launch_bounds__(256) void k1_sample_bf16(const float* __restrict__ Q,
                                                      const uint4* __restrict__ KB,
                                                      const int* __restrict__ idx,
                                                      float* __restrict__ M) {
    const int sb   = blockIdx.x;
    const int xcd  = sb & 7;
    const int li   = sb >> 3;
    const int bh   = (xcd << 2) + (li >> 9);
    const int rb   = li & 511;
    const int wave = threadIdx.x >> 6, lane = threadIdx.x & 63;
    const int q    = rb * 4 + wave;
    const int h    = bh & 15, b = bh >> 4;
    const int g    = lane >> 3, sub = lane & 7;

    const float4* Q4 = (const float4*)Q;
    const size_t rowQ = ((size_t)(b * L_ + q) * H_ + h) * 32;
    const int* ip = idx + q * S_;
    int kidx[5];
    #pragma unroll
    for (int s = 0; s < 5; ++s) kidx[s] = ip[s * 8 + g];

    const float4 qa0 = Q4[rowQ + 2 * sub];
    const float4 qa1 = Q4[rowQ + 2 * sub + 1];
    const float4 qb0 = Q4[rowQ + 16 + 2 * sub];
    const float4 qb1 = Q4[rowQ + 16 + 2 * sub + 1];

    uint4 kv[5][2];
    #pragma unroll
    for (int s = 0; s < 5; ++s) {
        const uint4* kr = KB + ((size_t)bh * L_ + kidx[s]) * 16;
        kv[s][0] = kr[sub];          // dims sub*8 .. +7
        kv[s][1] = kr[8 + sub];      // dims 64+sub*8 .. +7
    }
    __builtin_amdgcn_sched_barrier(0);

    float smax = -INFINITY, ssum = 0.0f;
    #pragma unroll
    for (int s = 0; s < 5; ++s) {
        float p = 0.f;
        {
            const uint4 u = kv[s][0];
            p += qa0.x * lo16(u.x) + qa0.y * hi16(u.x) + qa0.z * lo16(u.y) + qa0.w * hi16(u.y);
            p += qa1.x * lo16(u.z) + qa1.y * hi16(u.z) + qa1.z * lo16(u.w) + qa1.w * hi16(u.w);
        }
        {
            const uint4 u = kv[s][1];
            p += qb0.x * lo16(u.x) + qb0.y * hi16(u.x) + qb0.z * lo16(u.y) + qb0.w * hi16(u.y);
            p += qb1.x * lo16(u.z) + qb1.y * hi16(u.z) + qb1.z * lo16(u.w) + qb1.w * hi16(u.w);
        }
        p += __shfl_xor(p, 1);
        p += __shfl_xor(p, 2);
        p += __shfl_xor(p, 4);
        smax = fmaxf(smax, p);
        ssum += p;
    }
    #pragma unroll
    for (int o = 8; o < 64; o <<= 1) {
        smax = fmaxf(smax, __shfl_xor(smax, o));
        ssum += __shfl_xor(ssum, o);
    }
    if (lane == 0) M[(size_t)bh * L_ + q] = smax - ssum * (1.0f / L_);
}

// ---------------- k1 (fp32 fallback): r8 gather ------------------------------
__global__ __launch_bounds__(256) void k1_sample_f32(const float* __restrict__ Q,
                                                     const float* __restrict__ K,
                                                     const int* __restrict__ idx,
                                                     float* __restrict__ M) {
    const int sb   = blockIdx.x;
    const int xcd  = sb & 7;
    const int li   = sb >> 3;
    const int bh   = (xcd << 2) + (li >> 9);
    const int rb   = li & 511;
    const int wave = threadIdx.x >> 6, lane = threadIdx.x & 63;
    const int q    = rb * 4 + wave;
    const int h    = bh & 15, b = bh >> 4;
    const int g    = lane >> 3, sub = lane & 7;

    const float4* Q4 = (const float4*)Q;
    const float4* K4 = (const float4*)K;
    const size_t rowQ = ((size_t)(b * L_ + q) * H_ + h) * 32;
    const size_t kbase = ((size_t)b * L_ * H_ + h) * 32 + sub;
    const int* ip = idx + q * S_;
    int kidx[5];
    #pragma unroll
    for (int s = 0; s < 5; ++s) kidx[s] = ip[s * 8 + g];
    const float4 qv0 = Q4[rowQ + 0 + sub];
    const float4 qv1 = Q4[rowQ + 8 + sub];
    const float4 qv2 = Q4[rowQ + 16 + sub];
    const float4 qv3 = Q4[rowQ + 24 + sub];
    float4 kv[5][4];
    #pragma unroll
    for (int s = 0; s < 5; ++s) {
        const float4* kb = K4 + kbase + (size_t)kidx[s] * (H_ * 32);
        kv[s][0] = kb[0]; kv[s][1] = kb[8]; kv[s][2] = kb[16]; kv[s][3] = kb[24];
    }
    __builtin_amdgcn_sched_barrier(0);
    float smax = -INFINITY, ssum = 0.0f;
    #pragma unroll
    for (int s = 0; s < 5; ++s) {
        float p = qv0.x * kv[s][0].x + qv0.y * kv[s][0].y + qv0.z * kv[s][0].z + qv0.w * kv[s][0].w
                + qv1.x * kv[s][1].x + qv1.y * kv[s][1].y + qv1.z * kv[s][1].z + qv1.w * kv[s][1].w
                + qv2.x * kv[s][2].x + qv2.y * kv[s][2].y + qv2.z * kv[s][2].z + qv2.w * kv[s][2].w
                + qv3.x * kv[s][3].x + qv3.y * kv[s][3].y + qv3.z * kv[s][3].z + qv3.w * kv[s][3].w;
        p += __shfl_xor(p, 1);
        p += __shfl_xor(p, 2);
        p += __shfl_xor(p, 4);
        smax = fmaxf(smax, p);
        ssum += p;
    }
    #pragma unroll
    for (int o = 8; o < 64; o <<= 1) {
        smax = fmaxf(smax, __shfl_xor(smax, o));
        ssum += __shfl_xor(ssum, o);
    }
    if (lane == 0) M[(size_t)bh * L_ + q] = smax - ssum * (1.0f / L_);
}

// ---------------- k2: radix-T40 + exact refine + select + fill ---------------
// blocks 0..31 (bh): radix-select exact 40th of approx M -> candidates
//   C = {M_apx >= T40 - delta} (top-40-exact provably in C); recompute exact
//   fp32 M for C; rank (desc, tie->lowest idx) -> topk positions deterministic.
// blocks 32..543: fill out with vmean (16 slices x 128 rows per bh).
__global__ __launch_bounds__(1024) void k2_rank_refine_fill(const float* __restrict__ Mws,
                                                            const float* __restrict__ Q,
                                                            const float* __restrict__ K,
                                                            const int* __restrict__ idx,
                                                            const float* __restrict__ vpart,
                                                            int* __restrict__ topk,
                                                            float* __restrict__ out,
                                                            float delta) {
    const int bid = blockIdx.x, t = threadIdx.x;
    if (bid < 32) {
        __shared__ unsigned int ue[L_];
        __shared__ int hist[256], sscan[256];
        __shared__ int sh_chosen, sh_need, sh_nc;
        __shared__ int clist[CAND_];
        __shared__ float cMx[CAND_];
        __shared__ unsigned int cmaxe[CAND_];
        __shared__ float csum[CAND_];
        const int bh = bid, h = bh & 15, b = bh >> 4;
        const float* Mrow = Mws + (size_t)bh * L_;
        for (int i = t; i < L_; i += 1024) ue[i] = encf(Mrow[i]);
        if (t == 0) sh_nc = 0;
        __syncthreads();

        unsigned int prefix = 0; int need = NTOP_;
        for (int l = 3; l >= 0; --l) {
            if (t < 256) hist[t] = 0;
            __syncthreads();
            for (int i = t; i < L_; i += 1024) {
                const unsigned int u = ue[i];
                const bool match = (l == 3) || ((u >> (8 * (l + 1))) == prefix);
                if (match) atomicAdd(&hist[(u >> (8 * l)) & 255], 1);
            }
            __syncthreads();
            if (t < 256) sscan[t] = hist[t];
            __syncthreads();
            for (int off = 1; off < 256; off <<= 1) {
                int v = 0;
                if (t < 256 && t + off < 256) v = sscan[t + off];
                __syncthreads();
                if (t < 256) sscan[t] += v;
                __syncthreads();
            }
            if (t < 256) {
                const int above = sscan[t] - hist[t];
                if (above < need && need <= above + hist[t]) { sh_chosen = t; sh_need = need - above; }
            }
            __syncthreads();
            prefix = (prefix << 8) | (unsigned int)sh_chosen;
            need = sh_need;
            __syncthreads();
        }
        const unsigned int ethr = encf(decf(prefix) - delta);
        for (int i = t; i < L_; i += 1024) {
            if (ue[i] >= ethr) {
                const int p = atomicAdd(&sh_nc, 1);
                if (p < CAND_) clist[p] = i;
            }
        }
        __syncthreads();
        const int nc = min(sh_nc, CAND_);
        for (int i = t; i < CAND_; i += 1024) { cmaxe[i] = 0x007FFFFFu; csum[i] = 0.f; }
        __syncthreads();

        // exact fp32 recompute for candidates: 8-lane group per (cand, sample)
        const float4* Q4 = (const float4*)Q;
        const float4* K4 = (const float4*)K;
        const int grp = t >> 3, sub = t & 7;     // 128 groups
        for (int task = grp; task < nc * S_; task += 128) {
            const int ci = task / S_;
            const int s  = task - ci * S_;
            const int qq = clist[ci];
            const int ki = idx[qq * S_ + s];
            const float4* Kr = K4 + ((size_t)(b * L_ + ki) * H_ + h) * 32;
            const float4* Qr = Q4 + ((size_t)(b * L_ + qq) * H_ + h) * 32;
            float p = 0.f;
            #pragma unroll
            for (int qt2 = 0; qt2 < 4; ++qt2) {
                const float4 kv = Kr[qt2 * 8 + sub];
                const float4 qv = Qr[qt2 * 8 + sub];
                p += qv.x * kv.x + qv.y * kv.y + qv.z * kv.z + qv.w * kv.w;
            }
            p += __shfl_xor(p, 1);
            p += __shfl_xor(p, 2);
            p += __shfl_xor(p, 4);
            if (sub == 0) {
                atomicMax(&cmaxe[ci], encf(p));
                atomicAdd(&csum[ci], p);
            }
        }
        __syncthreads();
        if (t < nc) cMx[t] = decf(cmaxe[t]) - csum[t] * (1.0f / L_);
        __syncthreads();
        if (t < nc) {
            const float mi = cMx[t]; const int qi = clist[t];
            int rk = 0;
            for (int j = 0; j < nc; ++j) {
                const float mj = cMx[j];
                rk += (mj > mi) || (mj == mi && clist[j] < qi);
            }
            if (rk < NTOP_) topk[bh * NTOP_ + rk] = qi;
        }
    } else {
        __shared__ float red[1024];
        __shared__ float vmf[128];
        const int fb = bid - 32;              // 0..511
        const int bh = fb >> 4, sl = fb & 15; // 16 slices of 128 rows
        const int h = bh & 15, b = bh >> 4;
        const int d = t & 127, grp = t >> 7;
        float s = 0.f;
        #pragma unroll
        for (int c = grp * 4; c < grp * 4 + 4; ++c)
            s += vpart[(size_t)(bh * VCH_ + c) * D_ + d];
        red[t] = s;
        __syncthreads();
        if (t < 512) red[t] += red[t + 512];
        __syncthreads();
        if (t < 256) red[t] += red[t + 256];
        __syncthreads();
        if (t < 128) vmf[t] = (red[t] + red[t + 128]) * (1.0f / L_);
        __syncthreads();
        const float4 vm4 = *(const float4*)&vmf[(t & 31) * 4];
        float4* out4 = (float4*)out;
        const int q0 = sl * 128;
        #pragma unroll
        for (int k = 0; k < 4; ++k) {
            const int j = k * 1024 + t;
            const int r = j >> 5, c = j & 31;
            out4[((size_t)(b * L_ + q0 + r) * H_ + h) * 32 + c] = vm4;
        }
    }
}

// ---------------- K3: LDS-staged scores + partial softmax + partial PV -------
__global__ __launch_bounds__(256) void k_scorepv(const float* __restrict__ Q,
                                                 const float* __restrict__ K,
                                                 const float* __restrict__ V,
                                                 const int* __restrict__ topk,
                                                 float* __restrict__ pmax,
                                                 float* __restrict__ psum,
                                                 float* __restrict__ pout) {
    __shared__ float Qs[20 * D_];
    __shared__ float S[20 * 260];
    __shared__ float Ks[64 * 132];
    __shared__ float mrow[20];
    __shared__ int   tq[20];
    const int bid = blockIdx.x;
    const int xcd = bid & 7;
    const int loc = bid >> 3;
    const int bh  = (xcd << 2) + (loc >> 4);
    const int sub16 = loc & 15;
    const int kc  = sub16 >> 1;
    const int uh  = sub16 & 1;
    const int h   = bh & 15, b = bh >> 4;
    const int t   = threadIdx.x;

    if (t < 20) tq[t] = topk[bh * NTOP_ + uh * 20 + t];
    __syncthreads();

    {
        const float4* Q4 = (const float4*)Q;
        float4* Qs4 = (float4*)Qs;
        #pragma unroll
        for (int it = 0; it < 3; ++it) {
            const int i = it * 256 + t;
            if (i < 640) {
                const int u = i >> 5, dc = i & 31;
                Qs4[i] = Q4[((size_t)(b * L_ + tq[u]) * H_ + h) * 32 + dc];
            }
        }
    }
    __syncthreads();

    {
        const float4* K4 = (const float4*)K;
        const float4* Qs4 = (const float4*)Qs;
        float4* Ks4 = (float4*)Ks;
        const int r = t & 63, uq = t >> 6;
        for (int pass = 0; pass < 4; ++pass) {
            #pragma unroll
            for (int j = 0; j < 8; ++j) {
                const int gidx = j * 256 + t;
                const int row = gidx >> 5, c = gidx & 31;
                Ks4[row * 33 + c] =
                    K4[((size_t)(b * L_ + kc * CHK_ + pass * 64 + row) * H_ + h) * 32 + c];
            }
            __syncthreads();
            float acc[5] = {0.f, 0.f, 0.f, 0.f, 0.f};
            for (int dc = 0; dc < 32; ++dc) {
                const float4 kv = Ks4[r * 33 + dc];
                #pragma unroll
                for (int u5 = 0; u5 < 5; ++u5) {
                    const float4 qv = Qs4[(uq * 5 + u5) * 32 + dc];
                    acc[u5] += qv.x * kv.x + qv.y * kv.y + qv.z * kv.z + qv.w * kv.w;
                }
            }
            #pragma unroll
            for (int u5 = 0; u5 < 5; ++u5)
                S[(uq * 5 + u5) * 260 + pass * 64 + r] = acc[u5] * SCALE_;
            __syncthreads();
        }
    }

    {
        const int w = t >> 6, lane = t & 63;
        #pragma unroll
        for (int uu = 0; uu < 5; ++uu) {
            const int u = w * 5 + uu;
            const float* Sr = S + u * 260;
            float v = fmaxf(fmaxf(Sr[lane], Sr[lane + 64]),
                            fmaxf(Sr[lane + 128], Sr[lane + 192]));
            #pragma unroll
            for (int o = 1; o < 64; o <<= 1) v = fmaxf(v, __shfl_xor(v, o, 64));
            if (lane == 0) mrow[u] = v;
        }
    }
    __syncthreads();

    #pragma unroll
    for (int u = 0; u < 20; ++u) S[u * 260 + t] = __expf(S[u * 260 + t] - mrow[u]);
    __syncthreads();

    {
        const int w = t >> 6, lane = t & 63;
        #pragma unroll
        for (int uu = 0; uu < 5; ++uu) {
            const int u = w * 5 + uu;
            const float* Sr = S + u * 260;
            float v = Sr[lane] + Sr[lane + 64] + Sr[lane + 128] + Sr[lane + 192];
            #pragma unroll
            for (int o = 1; o < 64; o <<= 1) v += __shfl_xor(v, o, 64);
            if (lane == 0) {
                psum[(bh * NCH_ + kc) * NTOP_ + uh * 20 + u] = v;
                pmax[(bh * NCH_ + kc) * NTOP_ + uh * 20 + u] = mrow[u];
            }
        }
    }

    {
        const int d  = t & (D_ - 1);
        const int g  = t >> 7;
        const int u0 = g * 10;
        float acc2[10];
        #pragma unroll
        for (int u = 0; u < 10; ++u) acc2[u] = 0.0f;
        const float* Vb = V + ((size_t)(b * L_ + kc * CHK_) * H_ + h) * D_ + d;
        for (int kq = 0; kq < CHK_ / 4; ++kq) {
            const float v0 = Vb[(size_t)(kq * 4 + 0) * (H_ * D_)];
            const float v1 = Vb[(size_t)(kq * 4 + 1) * (H_ * D_)];
            const float v2 = Vb[(size_t)(kq * 4 + 2) * (H_ * D_)];
            const float v3 = Vb[(size_t)(kq * 4 + 3) * (H_ * D_)];
            #pragma unroll
            for (int u = 0; u < 10; ++u) {
                const float4 p = *(const float4*)&S[(u0 + u) * 260 + kq * 4];
                acc2[u] += p.x * v0 + p.y * v1 + p.z * v2 + p.w * v3;
            }
        }
        float* pb = pout + (((size_t)(bh * NCH_ + kc)) * NTOP_ + uh * 20 + u0) * D_ + d;
        #pragma unroll
        for (int u = 0; u < 10; ++u) pb[(size_t)u * D_] = acc2[u];
    }
}

// ---------------- K4: combine chunk partials, scatter to out -----------------
__global__ __launch_bounds__(128) void k_comb(const float* __restrict__ pmax,
                                              const float* __restrict__ psum,
                                              const float* __restrict__ pout,
                                              const int* __restrict__ topk,
                                              float* __restrict__ out) {
    const int bid = blockIdx.x;          // bh*40 + u
    const int bh  = bid / NTOP_;
    const int u   = bid - bh * NTOP_;
    const int h   = bh & 15, b = bh >> 4;
    const int t   = threadIdx.x;

    float pm[NCH_];
    float M = -INFINITY;
    #pragma unroll
    for (int c = 0; c < NCH_; ++c) {
        pm[c] = pmax[(bh * NCH_ + c) * NTOP_ + u];
        M = fmaxf(M, pm[c]);
    }
    float ssum = 0.0f, o = 0.0f;
    #pragma unroll
    for (int c = 0; c < NCH_; ++c) {
        const float w = __expf(pm[c] - M);
        ssum += psum[(bh * NCH_ + c) * NTOP_ + u] * w;
        o += pout[((size_t)(bh * NCH_ + c) * NTOP_ + u) * D_ + t] * w;
    }
    const int qi = topk[bh * NTOP_ + u];
    out[((size_t)(b * L_ + qi) * H_ + h) * D_ + t] = o / ssum;
}

extern "C" void kernel_launch(void* const* d_in, const int* in_sizes, int n_in,
                              void* d_out, int out_size, void* d_ws, size_t ws_size,
                              hipStream_t stream) {
    const float* Q  = (const float*)d_in[0];
    const float* K  = (const float*)d_in[1];
    const float* V  = (const float*)d_in[2];
    const int* idx  = (const int*)d_in[3];
    float* out      = (float*)d_out;

    char* ws = (char*)d_ws;
    size_t off = 0;
    float* Mws   = (float*)(ws + off); off += (size_t)65536 * 4;
    float* vpart = (float*)(ws + off); off += (size_t)1024 * 128 * 4;
    int*   topk  = (int*)(ws + off);   off += 1280 * 4;
    float* pmax  = (float*)(ws + off); off += (size_t)256 * 40 * 4;
    float* psum  = (float*)(ws + off); off += (size_t)256 * 40 * 4;
    float* pout  = (float*)(ws + off); off += (size_t)256 * 40 * 128 * 4;
    unsigned int* Kbf = (unsigned int*)(ws + off);
    const size_t kbf_bytes = (size_t)32 * L_ * D_ * 2;      // 16.8 MB
    const bool use_bf16 = (ws_size >= off + kbf_bytes);

    if (use_bf16)
        hipLaunchKernelGGL(kpack, dim3(256), dim3(256), 0, stream, K, Kbf);
    hipLaunchKernelGGL(k0_vpart, dim3(1024), dim3(256), 0, stream, V, vpart);
    if (use_bf16)
        hipLaunchKernelGGL(k1_sample_bf16, dim3(16384), dim3(256), 0, stream,
                           Q, (const uint4*)Kbf, idx, Mws);
    else
        hipLaunchKernelGGL(k1_sample_f32, dim3(16384), dim3(256), 0, stream,
                           Q, K, idx, Mws);
    hipLaunchKernelGGL(k2_rank_refine_fill, dim3(32 + 512), dim3(1024), 0, stream,
                       Mws, Q, K, idx, vpart, topk, out, use_bf16 ? 2.0f : 0.01f);
    hipLaunchKernelGGL(k_scorepv, dim3(512), dim3(256), 0, stream,
                       Q, K, V, topk, pmax, psum, pout);
    hipLaunchKernelGGL(k_comb, dim3(1280), dim3(128), 0, stream,
                       pmax, psum, pout, topk, out);
}

// Round 10
// 138.231 us; speedup vs baseline: 1.1111x; 1.1111x over previous
//
#include <hip/hip_runtime.h>
#include <math.h>

#define B_    2
#define L_    2048
#define H_    16
#define D_    128
#define S_    40
#define NTOP_ 40
#define NCH_  8        // key chunks for attention
#define CHK_  256      // keys per chunk (attention)
#define VCH_  32       // L chunks for vmean
#define CAND_ 512      // refine candidate capacity

#define SCALE_ 0.08838834764831843f  // 1/sqrt(128)

// monotone float<->uint encoding (order-preserving, incl. negatives)
__device__ __forceinline__ unsigned int encf(float f) {
    unsigned int u = __float_as_uint(f);
    return (u & 0x80000000u) ? ~u : (u | 0x80000000u);
}
__device__ __forceinline__ float decf(unsigned int e) {
    unsigned int u = (e & 0x80000000u) ? (e ^ 0x80000000u) : ~e;
    return __uint_as_float(u);
}
__device__ __forceinline__ unsigned int bfpack(float a, float b) {  // RNE bf16 pair
    unsigned int ua = __float_as_uint(a); ua = (ua + 0x7fffu + ((ua >> 16) & 1u)) >> 16;
    unsigned int ub = __float_as_uint(b); ub = (ub + 0x7fffu + ((ub >> 16) & 1u)) >> 16;
    return ua | (ub << 16);
}
__device__ __forceinline__ float lo16(unsigned int u) { return __uint_as_float(u << 16); }
__device__ __forceinline__ float hi16(unsigned int u) { return __uint_as_float(u & 0xffff0000u); }

// ---------------- kPV: fused K->bf16 pack + V partial sums -------------------
// blocks 0..255: pack K rows to bf16 (Kbf[(bh*L+ki)*128 + d], 256 B rows).
// blocks 256..1279: V chunk partial sums.
__global__ __launch_bounds__(256) void k_pack_vpart(const float* __restrict__ K,
                                                    const float* __restrict__ V,
                                                    unsigned int* __restrict__ Kbf,
                                                    float* __restrict__ vpart) {
    const int bid = blockIdx.x, t = threadIdx.x;
    if (bid < 256) {
        const int bh = bid >> 3, kc = bid & 7;
        const int h = bh & 15, b = bh >> 4;
        const float4* K4 = (const float4*)K;
        uint2* out2 = (uint2*)Kbf;
        for (int j = 0; j < 32; ++j) {
            const int g = j * 256 + t;                 // 0..8191
            const int row = g >> 5, c = g & 31;
            const float4 v = K4[((size_t)(b * L_ + kc * 256 + row) * H_ + h) * 32 + c];
            out2[(size_t)(bh * L_ + kc * 256 + row) * 32 + c] =
                make_uint2(bfpack(v.x, v.y), bfpack(v.z, v.w));
        }
    } else {
        __shared__ float red[256];
        const int vbid = bid - 256;          // bh*VCH_ + lc
        const int bh  = vbid >> 5;
        const int lc  = vbid & (VCH_ - 1);
        const int h   = bh & 15, b = bh >> 4;
        const int d   = t & (D_ - 1);
        const int sub = t >> 7;
        float acc = 0.0f;
        const int l0 = lc * (L_ / VCH_);
        for (int l = l0 + sub; l < l0 + L_ / VCH_; l += 2)
            acc += V[((size_t)(b * L_ + l) * H_ + h) * D_ + d];
        red[t] = acc;
        __syncthreads();
        if (t < D_) vpart[(size_t)vbid * D_ + t] = red[t] + red[t + 128];
    }
}

// ---------------- k1 (bf16): sampled approx M --------------------------------
__global__ __launch_bounds__(256) void k1_sample_bf16(const float* __restrict__ Q,
                                                      const uint4* __restrict__ KB,
                                                      const int* __restrict__ idx,
                                                      float* __restrict__ M) {
    const int sb   = blockIdx.x;
    const int xcd  = sb & 7;
    const int li   = sb >> 3;
    const int bh   = (xcd << 2) + (li >> 9);
    const int rb   = li & 511;
    const int wave = threadIdx.x >> 6, lane = threadIdx.x & 63;
    const int q    = rb * 4 + wave;
    const int h    = bh & 15, b = bh >> 4;
    const int g    = lane >> 3, sub = lane & 7;

    const float4* Q4 = (const float4*)Q;
    const size_t rowQ = ((size_t)(b * L_ + q) * H_ + h) * 32;
    const int* ip = idx + q * S_;
    int kidx[5];
    #pragma unroll
    for (int s = 0; s < 5; ++s) kidx[s] = ip[s * 8 + g];

    const float4 qa0 = Q4[rowQ + 2 * sub];
    const float4 qa1 = Q4[rowQ + 2 * sub + 1];
    const float4 qb0 = Q4[rowQ + 16 + 2 * sub];
    const float4 qb1 = Q4[rowQ + 16 + 2 * sub + 1];

    uint4 kv[5][2];
    #pragma unroll
    for (int s = 0; s < 5; ++s) {
        const uint4* kr = KB + ((size_t)bh * L_ + kidx[s]) * 16;
        kv[s][0] = kr[sub];
        kv[s][1] = kr[8 + sub];
    }
    __builtin_amdgcn_sched_barrier(0);

    float smax = -INFINITY, ssum = 0.0f;
    #pragma unroll
    for (int s = 0; s < 5; ++s) {
        float p = 0.f;
        {
            const uint4 u = kv[s][0];
            p += qa0.x * lo16(u.x) + qa0.y * hi16(u.x) + qa0.z * lo16(u.y) + qa0.w * hi16(u.y);
            p += qa1.x * lo16(u.z) + qa1.y * hi16(u.z) + qa1.z * lo16(u.w) + qa1.w * hi16(u.w);
        }
        {
            const uint4 u = kv[s][1];
            p += qb0.x * lo16(u.x) + qb0.y * hi16(u.x) + qb0.z * lo16(u.y) + qb0.w * hi16(u.y);
            p += qb1.x * lo16(u.z) + qb1.y * hi16(u.z) + qb1.z * lo16(u.w) + qb1.w * hi16(u.w);
        }
        p += __shfl_xor(p, 1);
        p += __shfl_xor(p, 2);
        p += __shfl_xor(p, 4);
        smax = fmaxf(smax, p);
        ssum += p;
    }
    #pragma unroll
    for (int o = 8; o < 64; o <<= 1) {
        smax = fmaxf(smax, __shfl_xor(smax, o));
        ssum += __shfl_xor(ssum, o);
    }
    if (lane == 0) M[(size_t)bh * L_ + q] = smax - ssum * (1.0f / L_);
}

// ---------------- k1 (fp32 fallback) -----------------------------------------
__global__ __launch_bounds__(256) void k1_sample_f32(const float* __restrict__ Q,
                                                     const float* __restrict__ K,
                                                     const int* __restrict__ idx,
                                                     float* __restrict__ M) {
    const int sb   = blockIdx.x;
    const int xcd  = sb & 7;
    const int li   = sb >> 3;
    const int bh   = (xcd << 2) + (li >> 9);
    const int rb   = li & 511;
    const int wave = threadIdx.x >> 6, lane = threadIdx.x & 63;
    const int q    = rb * 4 + wave;
    const int h    = bh & 15, b = bh >> 4;
    const int g    = lane >> 3, sub = lane & 7;

    const float4* Q4 = (const float4*)Q;
    const float4* K4 = (const float4*)K;
    const size_t rowQ = ((size_t)(b * L_ + q) * H_ + h) * 32;
    const size_t kbase = ((size_t)b * L_ * H_ + h) * 32 + sub;
    const int* ip = idx + q * S_;
    int kidx[5];
    #pragma unroll
    for (int s = 0; s < 5; ++s) kidx[s] = ip[s * 8 + g];
    const float4 qv0 = Q4[rowQ + 0 + sub];
    const float4 qv1 = Q4[rowQ + 8 + sub];
    const float4 qv2 = Q4[rowQ + 16 + sub];
    const float4 qv3 = Q4[rowQ + 24 + sub];
    float4 kv[5][4];
    #pragma unroll
    for (int s = 0; s < 5; ++s) {
        const float4* kb = K4 + kbase + (size_t)kidx[s] * (H_ * 32);
        kv[s][0] = kb[0]; kv[s][1] = kb[8]; kv[s][2] = kb[16]; kv[s][3] = kb[24];
    }
    __builtin_amdgcn_sched_barrier(0);
    float smax = -INFINITY, ssum = 0.0f;
    #pragma unroll
    for (int s = 0; s < 5; ++s) {
        float p = qv0.x * kv[s][0].x + qv0.y * kv[s][0].y + qv0.z * kv[s][0].z + qv0.w * kv[s][0].w
                + qv1.x * kv[s][1].x + qv1.y * kv[s][1].y + qv1.z * kv[s][1].z + qv1.w * kv[s][1].w
                + qv2.x * kv[s][2].x + qv2.y * kv[s][2].y + qv2.z * kv[s][2].z + qv2.w * kv[s][2].w
                + qv3.x * kv[s][3].x + qv3.y * kv[s][3].y + qv3.z * kv[s][3].z + qv3.w * kv[s][3].w;
        p += __shfl_xor(p, 1);
        p += __shfl_xor(p, 2);
        p += __shfl_xor(p, 4);
        smax = fmaxf(smax, p);
        ssum += p;
    }
    #pragma unroll
    for (int o = 8; o < 64; o <<= 1) {
        smax = fmaxf(smax, __shfl_xor(smax, o));
        ssum += __shfl_xor(ssum, o);
    }
    if (lane == 0) M[(size_t)bh * L_ + q] = smax - ssum * (1.0f / L_);
}

// ---------------- k2: radix-T40 + exact refine + select + fill ---------------
__global__ __launch_bounds__(1024) void k2_rank_refine_fill(const float* __restrict__ Mws,
                                                            const float* __restrict__ Q,
                                                            const float* __restrict__ K,
                                                            const int* __restrict__ idx,
                                                            const float* __restrict__ vpart,
                                                            int* __restrict__ topk,
                                                            float* __restrict__ out,
                                                            float delta) {
    const int bid = blockIdx.x, t = threadIdx.x;
    if (bid < 32) {
        __shared__ unsigned int ue[L_];
        __shared__ int hist[256], sscan[256];
        __shared__ int sh_chosen, sh_need, sh_nc;
        __shared__ int clist[CAND_];
        __shared__ float cMx[CAND_];
        __shared__ unsigned int cmaxe[CAND_];
        __shared__ float csum[CAND_];
        const int bh = bid, h = bh & 15, b = bh >> 4;
        const float* Mrow = Mws + (size_t)bh * L_;
        for (int i = t; i < L_; i += 1024) ue[i] = encf(Mrow[i]);
        if (t == 0) sh_nc = 0;
        __syncthreads();

        unsigned int prefix = 0; int need = NTOP_;
        for (int l = 3; l >= 0; --l) {
            if (t < 256) hist[t] = 0;
            __syncthreads();
            for (int i = t; i < L_; i += 1024) {
                const unsigned int u = ue[i];
                const bool match = (l == 3) || ((u >> (8 * (l + 1))) == prefix);
                if (match) atomicAdd(&hist[(u >> (8 * l)) & 255], 1);
            }
            __syncthreads();
            if (t < 256) sscan[t] = hist[t];
            __syncthreads();
            for (int off = 1; off < 256; off <<= 1) {
                int v = 0;
                if (t < 256 && t + off < 256) v = sscan[t + off];
                __syncthreads();
                if (t < 256) sscan[t] += v;
                __syncthreads();
            }
            if (t < 256) {
                const int above = sscan[t] - hist[t];
                if (above < need && need <= above + hist[t]) { sh_chosen = t; sh_need = need - above; }
            }
            __syncthreads();
            prefix = (prefix << 8) | (unsigned int)sh_chosen;
            need = sh_need;
            __syncthreads();
        }
        const unsigned int ethr = encf(decf(prefix) - delta);
        for (int i = t; i < L_; i += 1024) {
            if (ue[i] >= ethr) {
                const int p = atomicAdd(&sh_nc, 1);
                if (p < CAND_) clist[p] = i;
            }
        }
        __syncthreads();
        const int nc = min(sh_nc, CAND_);
        for (int i = t; i < CAND_; i += 1024) { cmaxe[i] = 0x007FFFFFu; csum[i] = 0.f; }
        __syncthreads();

        const float4* Q4 = (const float4*)Q;
        const float4* K4 = (const float4*)K;
        const int grp = t >> 3, sub = t & 7;     // 128 groups
        for (int task = grp; task < nc * S_; task += 128) {
            const int ci = task / S_;
            const int s  = task - ci * S_;
            const int qq = clist[ci];
            const int ki = idx[qq * S_ + s];
            const float4* Kr = K4 + ((size_t)(b * L_ + ki) * H_ + h) * 32;
            const float4* Qr = Q4 + ((size_t)(b * L_ + qq) * H_ + h) * 32;
            float p = 0.f;
            #pragma unroll
            for (int qt2 = 0; qt2 < 4; ++qt2) {
                const float4 kv = Kr[qt2 * 8 + sub];
                const float4 qv = Qr[qt2 * 8 + sub];
                p += qv.x * kv.x + qv.y * kv.y + qv.z * kv.z + qv.w * kv.w;
            }
            p += __shfl_xor(p, 1);
            p += __shfl_xor(p, 2);
            p += __shfl_xor(p, 4);
            if (sub == 0) {
                atomicMax(&cmaxe[ci], encf(p));
                atomicAdd(&csum[ci], p);
            }
        }
        __syncthreads();
        if (t < nc) cMx[t] = decf(cmaxe[t]) - csum[t] * (1.0f / L_);
        __syncthreads();
        if (t < nc) {
            const float mi = cMx[t]; const int qi = clist[t];
            int rk = 0;
            for (int j = 0; j < nc; ++j) {
                const float mj = cMx[j];
                rk += (mj > mi) || (mj == mi && clist[j] < qi);
            }
            if (rk < NTOP_) topk[bh * NTOP_ + rk] = qi;
        }
    } else {
        __shared__ float red[1024];
        __shared__ float vmf[128];
        const int fb = bid - 32;              // 0..511
        const int bh = fb >> 4, sl = fb & 15; // 16 slices of 128 rows
        const int h = bh & 15, b = bh >> 4;
        const int d = t & 127, grp = t >> 7;
        float s = 0.f;
        #pragma unroll
        for (int c = grp * 4; c < grp * 4 + 4; ++c)
            s += vpart[(size_t)(bh * VCH_ + c) * D_ + d];
        red[t] = s;
        __syncthreads();
        if (t < 512) red[t] += red[t + 512];
        __syncthreads();
        if (t < 256) red[t] += red[t + 256];
        __syncthreads();
        if (t < 128) vmf[t] = (red[t] + red[t + 128]) * (1.0f / L_);
        __syncthreads();
        const float4 vm4 = *(const float4*)&vmf[(t & 31) * 4];
        float4* out4 = (float4*)out;
        const int q0 = sl * 128;
        #pragma unroll
        for (int k = 0; k < 4; ++k) {
            const int j = k * 1024 + t;
            const int r = j >> 5, c = j & 31;
            out4[((size_t)(b * L_ + q0 + r) * H_ + h) * 32 + c] = vm4;
        }
    }
}

// ---------------- K3: register-tiled scores + softmax + PV -------------------
// Block = (bh, kc, uh), XCD-swizzled. NO K staging: scores read K directly
// from global (each (key,dc) fragment read once per block, 4-lane broadcast);
// thread = (kq4 of 4 keys, ug of 5 u), per dc: 5 Q-LDS + 4 K-global reads for
// 160 FLOP. PV: thread = (wave g of 5 u, d-pair), per 4-key iter: 5 S-LDS +
// 4 V-float2 for 80 FLOP. LDS instrs per thread ~520 (was ~1280) -> breaks
// the ds_read_b128 throughput wall that pinned r9 at 55 us.
__global__ __launch_bounds__(256) void k_scorepv(const float* __restrict__ Q,
                                                 const float* __restrict__ K,
                                                 const float* __restrict__ V,
                                                 const int* __restrict__ topk,
                                                 float* __restrict__ pmax,
                                                 float* __restrict__ psum,
                                                 float* __restrict__ pout) {
    __shared__ float Qs[20 * 132];          // 10.6 KB (132-stride: ug bank spread)
    __shared__ float S[20 * 260];           // 20.8 KB
    __shared__ float mrow[20];
    __shared__ int   tq[20];
    const int bid = blockIdx.x;
    const int xcd = bid & 7;
    const int loc = bid >> 3;               // 0..63
    const int bh  = (xcd << 2) + (loc >> 4);
    const int sub16 = loc & 15;
    const int kc  = sub16 >> 1;
    const int uh  = sub16 & 1;
    const int h   = bh & 15, b = bh >> 4;
    const int t   = threadIdx.x;

    if (t < 20) tq[t] = topk[bh * NTOP_ + uh * 20 + t];
    __syncthreads();

    // stage 20 Q rows -> Qs[u*132 + d]
    {
        const float4* Q4 = (const float4*)Q;
        #pragma unroll
        for (int it = 0; it < 3; ++it) {
            const int i = it * 256 + t;
            if (i < 640) {
                const int u = i >> 5, dc = i & 31;
                *(float4*)&Qs[u * 132 + dc * 4] =
                    Q4[((size_t)(b * L_ + tq[u]) * H_ + h) * 32 + dc];
            }
        }
    }
    __syncthreads();

    // scores: thread = (kq4 = t>>2 owns keys kq4*4..+3, ug = t&3 owns u ug*5..+5)
    {
        const int kq4 = t >> 2, ug = t & 3;
        float acc[4][5];
        #pragma unroll
        for (int j = 0; j < 4; ++j)
            #pragma unroll
            for (int uu = 0; uu < 5; ++uu) acc[j][uu] = 0.f;
        const float4* Kb = (const float4*)K +
            ((size_t)(b * L_ + kc * CHK_ + kq4 * 4) * H_ + h) * 32;
        for (int dc = 0; dc < 32; ++dc) {
            float4 qv[5];
            #pragma unroll
            for (int uu = 0; uu < 5; ++uu)
                qv[uu] = *(const float4*)&Qs[(ug * 5 + uu) * 132 + dc * 4];
            #pragma unroll
            for (int j = 0; j < 4; ++j) {
                const float4 kv = Kb[(size_t)j * (H_ * 32) + dc];
                #pragma unroll
                for (int uu = 0; uu < 5; ++uu)
                    acc[j][uu] += qv[uu].x * kv.x + qv[uu].y * kv.y
                                + qv[uu].z * kv.z + qv[uu].w * kv.w;
            }
        }
        #pragma unroll
        for (int j = 0; j < 4; ++j)
            #pragma unroll
            for (int uu = 0; uu < 5; ++uu)
                S[(ug * 5 + uu) * 260 + kq4 * 4 + j] = acc[j][uu] * SCALE_;
    }
    __syncthreads();

    // per-u max (wave w handles 5 u's)
    {
        const int w = t >> 6, lane = t & 63;
        #pragma unroll
        for (int uu = 0; uu < 5; ++uu) {
            const int u = w * 5 + uu;
            const float* Sr = S + u * 260;
            float v = fmaxf(fmaxf(Sr[lane], Sr[lane + 64]),
                            fmaxf(Sr[lane + 128], Sr[lane + 192]));
            #pragma unroll
            for (int o = 1; o < 64; o <<= 1) v = fmaxf(v, __shfl_xor(v, o, 64));
            if (lane == 0) mrow[u] = v;
        }
    }
    __syncthreads();

    #pragma unroll
    for (int u = 0; u < 20; ++u) S[u * 260 + t] = __expf(S[u * 260 + t] - mrow[u]);
    __syncthreads();

    // per-u sum -> psum / pmax
    {
        const int w = t >> 6, lane = t & 63;
        #pragma unroll
        for (int uu = 0; uu < 5; ++uu) {
            const int u = w * 5 + uu;
            const float* Sr = S + u * 260;
            float v = Sr[lane] + Sr[lane + 64] + Sr[lane + 128] + Sr[lane + 192];
            #pragma unroll
            for (int o = 1; o < 64; o <<= 1) v += __shfl_xor(v, o, 64);
            if (lane == 0) {
                psum[(bh * NCH_ + kc) * NTOP_ + uh * 20 + u] = v;
                pmax[(bh * NCH_ + kc) * NTOP_ + uh * 20 + u] = mrow[u];
            }
        }
    }

    // PV: wave g owns u g*5..+5; lane d2 owns dims {2*d2, 2*d2+1}
    {
        const int g = t >> 6, d2 = t & 63;
        const int u0 = g * 5;
        float accA[5], accB[5];
        #pragma unroll
        for (int uu = 0; uu < 5; ++uu) { accA[uu] = 0.f; accB[uu] = 0.f; }
        const float2* Vb = (const float2*)(V + ((size_t)(b * L_ + kc * CHK_) * H_ + h) * D_) + d2;
        for (int kq = 0; kq < CHK_ / 4; ++kq) {
            float2 v0 = Vb[(size_t)(kq * 4 + 0) * (H_ * D_ / 2)];
            float2 v1 = Vb[(size_t)(kq * 4 + 1) * (H_ * D_ / 2)];
            float2 v2 = Vb[(size_t)(kq * 4 + 2) * (H_ * D_ / 2)];
            float2 v3 = Vb[(size_t)(kq * 4 + 3) * (H_ * D_ / 2)];
            #pragma unroll
            for (int uu = 0; uu < 5; ++uu) {
                const float4 p = *(const float4*)&S[(u0 + uu) * 260 + kq * 4];
                accA[uu] += p.x * v0.x + p.y * v1.x + p.z * v2.x + p.w * v3.x;
                accB[uu] += p.x * v0.y + p.y * v1.y + p.z * v2.y + p.w * v3.y;
            }
        }
        float* pb = pout + (((size_t)(bh * NCH_ + kc)) * NTOP_ + uh * 20 + u0) * D_ + d2 * 2;
        #pragma unroll
        for (int uu = 0; uu < 5; ++uu)
            *(float2*)&pb[(size_t)uu * D_] = make_float2(accA[uu], accB[uu]);
    }
}

// ---------------- K4: combine chunk partials, scatter to out -----------------
__global__ __launch_bounds__(128) void k_comb(const float* __restrict__ pmax,
                                              const float* __restrict__ psum,
                                              const float* __restrict__ pout,
                                              const int* __restrict__ topk,
                                              float* __restrict__ out) {
    const int bid = blockIdx.x;          // bh*40 + u
    const int bh  = bid / NTOP_;
    const int u   = bid - bh * NTOP_;
    const int h   = bh & 15, b = bh >> 4;
    const int t   = threadIdx.x;

    float pm[NCH_];
    float M = -INFINITY;
    #pragma unroll
    for (int c = 0; c < NCH_; ++c) {
        pm[c] = pmax[(bh * NCH_ + c) * NTOP_ + u];
        M = fmaxf(M, pm[c]);
    }
    float ssum = 0.0f, o = 0.0f;
    #pragma unroll
    for (int c = 0; c < NCH_; ++c) {
        const float w = __expf(pm[c] - M);
        ssum += psum[(bh * NCH_ + c) * NTOP_ + u] * w;
        o += pout[((size_t)(bh * NCH_ + c) * NTOP_ + u) * D_ + t] * w;
    }
    const int qi = topk[bh * NTOP_ + u];
    out[((size_t)(b * L_ + qi) * H_ + h) * D_ + t] = o / ssum;
}

extern "C" void kernel_launch(void* const* d_in, const int* in_sizes, int n_in,
                              void* d_out, int out_size, void* d_ws, size_t ws_size,
                              hipStream_t stream) {
    const float* Q  = (const float*)d_in[0];
    const float* K  = (const float*)d_in[1];
    const float* V  = (const float*)d_in[2];
    const int* idx  = (const int*)d_in[3];
    float* out      = (float*)d_out;

    char* ws = (char*)d_ws;
    size_t off = 0;
    float* Mws   = (float*)(ws + off); off += (size_t)65536 * 4;
    float* vpart = (float*)(ws + off); off += (size_t)1024 * 128 * 4;
    int*   topk  = (int*)(ws + off);   off += 1280 * 4;
    float* pmax  = (float*)(ws + off); off += (size_t)256 * 40 * 4;
    float* psum  = (float*)(ws + off); off += (size_t)256 * 40 * 4;
    float* pout  = (float*)(ws + off); off += (size_t)256 * 40 * 128 * 4;
    unsigned int* Kbf = (unsigned int*)(ws + off);
    const size_t kbf_bytes = (size_t)32 * L_ * D_ * 2;      // 16.8 MB
    const bool use_bf16 = (ws_size >= off + kbf_bytes);

    if (use_bf16) {
        hipLaunchKernelGGL(k_pack_vpart, dim3(1280), dim3(256), 0, stream, K, V, Kbf, vpart);
        hipLaunchKernelGGL(k1_sample_bf16, dim3(16384), dim3(256), 0, stream,
                           Q, (const uint4*)Kbf, idx, Mws);
    } else {
        hipLaunchKernelGGL(k_pack_vpart, dim3(1280), dim3(256), 0, stream, K, V, Kbf, vpart);
        hipLaunchKernelGGL(k1_sample_f32, dim3(16384), dim3(256), 0, stream,
                           Q, K, idx, Mws);
    }
    hipLaunchKernelGGL(k2_rank_refine_fill, dim3(32 + 512), dim3(1024), 0, stream,
                       Mws, Q, K, idx, vpart, topk, out, use_bf16 ? 2.0f : 0.01f);
    hipLaunchKernelGGL(k_scorepv, dim3(512), dim3(256), 0, stream,
                       Q, K, V, topk, pmax, psum, pout);
    hipLaunchKernelGGL(k_comb, dim3(1280), dim3(128), 0, stream,
                       pmax, psum, pout, topk, out);
}

// Round 11
// 127.358 us; speedup vs baseline: 1.2059x; 1.0854x over previous
//
#include <hip/hip_runtime.h>
#include <math.h>

#define B_    2
#define L_    2048
#define H_    16
#define D_    128
#define S_    40
#define NTOP_ 40
#define NCH_  8        // key chunks for attention
#define CHK_  256      // keys per chunk (attention)
#define VCH_  32       // L chunks for vmean
#define CAND_ 512      // refine candidate capacity

#define SCALE_ 0.08838834764831843f  // 1/sqrt(128)

typedef _Float16 half2_t __attribute__((ext_vector_type(2)));

__device__ __forceinline__ half2_t as_h2(unsigned int u) {
    union { unsigned int u; half2_t h; } x; x.u = u; return x.h;
}
__device__ __forceinline__ unsigned int h2pack(float a, float b) {  // RNE f16 pair
    union { half2_t h; unsigned int u; } x;
    x.h[0] = (_Float16)a; x.h[1] = (_Float16)b; return x.u;
}
#if __has_builtin(__builtin_amdgcn_fdot2)
__device__ __forceinline__ float FDOT2(half2_t a, half2_t b, float c) {
    return __builtin_amdgcn_fdot2(a, b, c, false);
}
#else
__device__ __forceinline__ float FDOT2(half2_t a, half2_t b, float c) {
    return c + (float)a[0] * (float)b[0] + (float)a[1] * (float)b[1];
}
#endif

// monotone float<->uint encoding (order-preserving, incl. negatives)
__device__ __forceinline__ unsigned int encf(float f) {
    unsigned int u = __float_as_uint(f);
    return (u & 0x80000000u) ? ~u : (u | 0x80000000u);
}
__device__ __forceinline__ float decf(unsigned int e) {
    unsigned int u = (e & 0x80000000u) ? (e ^ 0x80000000u) : ~e;
    return __uint_as_float(u);
}

// ---------------- kpack: K -> f16 rows Kf[(bh*L+ki)*128 + d] (256 B rows) ----
__global__ __launch_bounds__(256) void kpack(const float* __restrict__ K,
                                             unsigned int* __restrict__ Kf) {
    const int bid = blockIdx.x, t = threadIdx.x;   // 256 blocks = (bh, kc of 256)
    const int bh = bid >> 3, kc = bid & 7;
    const int h = bh & 15, b = bh >> 4;
    const float4* K4 = (const float4*)K;
    uint2* out2 = (uint2*)Kf;
    for (int j = 0; j < 32; ++j) {
        const int g = j * 256 + t;                 // 0..8191
        const int row = g >> 5, c = g & 31;
        const float4 v = K4[((size_t)(b * L_ + kc * 256 + row) * H_ + h) * 32 + c];
        out2[(size_t)(bh * L_ + kc * 256 + row) * 32 + c] =
            make_uint2(h2pack(v.x, v.y), h2pack(v.z, v.w));
    }
}

// ---------------- k1: fused vpartial + f16 sampled approx M ------------------
// blocks 0..1023: V chunk partial sums (HBM-bound, overlaps the gather phase).
// blocks 1024..17407: sampleM. One wave per q-row; 8 lanes span D; each
// 8-lane group owns one sample; dot via v_dot2_f32_f16 (4x less VALU than
// bf16 unpack+fma). XCD-pinned bh slices. 2 x 128B segments per (q,s) pair.
__global__ __launch_bounds__(256) void k1_sample_f16(const float* __restrict__ Q,
                                                     const uint4* __restrict__ KF,
                                                     const float* __restrict__ V,
                                                     const int* __restrict__ idx,
                                                     float* __restrict__ M,
                                                     float* __restrict__ vpart) {
    const int bid = blockIdx.x;
    const int t   = threadIdx.x;

    if (bid < 1024) {
        __shared__ float red[256];
        const int vbid = bid;                // bh*VCH_ + lc
        const int bh  = vbid >> 5;
        const int lc  = vbid & (VCH_ - 1);
        const int h   = bh & 15, b = bh >> 4;
        const int d   = t & (D_ - 1);
        const int sub = t >> 7;
        float acc = 0.0f;
        const int l0 = lc * (L_ / VCH_);
        for (int l = l0 + sub; l < l0 + L_ / VCH_; l += 2)
            acc += V[((size_t)(b * L_ + l) * H_ + h) * D_ + d];
        red[t] = acc;
        __syncthreads();
        if (t < D_) vpart[(size_t)vbid * D_ + t] = red[t] + red[t + 128];
        return;
    }

    const int sb   = bid - 1024;
    const int xcd  = sb & 7;
    const int li   = sb >> 3;
    const int bh   = (xcd << 2) + (li >> 9);
    const int rb   = li & 511;
    const int wave = t >> 6, lane = t & 63;
    const int q    = rb * 4 + wave;
    const int h    = bh & 15, b = bh >> 4;
    const int g    = lane >> 3, sub = lane & 7;

    const float4* Q4 = (const float4*)Q;
    const size_t rowQ = ((size_t)(b * L_ + q) * H_ + h) * 32;
    const int* ip = idx + q * S_;
    int kidx[5];
    #pragma unroll
    for (int s = 0; s < 5; ++s) kidx[s] = ip[s * 8 + g];

    const float4 qa0 = Q4[rowQ + 2 * sub];
    const float4 qa1 = Q4[rowQ + 2 * sub + 1];
    const float4 qb0 = Q4[rowQ + 16 + 2 * sub];
    const float4 qb1 = Q4[rowQ + 16 + 2 * sub + 1];

    uint4 kv[5][2];
    #pragma unroll
    for (int s = 0; s < 5; ++s) {
        const uint4* kr = KF + ((size_t)bh * L_ + kidx[s]) * 16;
        kv[s][0] = kr[sub];          // dims 8sub..8sub+7
        kv[s][1] = kr[8 + sub];      // dims 64+8sub..+7
    }
    __builtin_amdgcn_sched_barrier(0);

    half2_t qh[8];
    qh[0][0] = (_Float16)qa0.x; qh[0][1] = (_Float16)qa0.y;
    qh[1][0] = (_Float16)qa0.z; qh[1][1] = (_Float16)qa0.w;
    qh[2][0] = (_Float16)qa1.x; qh[2][1] = (_Float16)qa1.y;
    qh[3][0] = (_Float16)qa1.z; qh[3][1] = (_Float16)qa1.w;
    qh[4][0] = (_Float16)qb0.x; qh[4][1] = (_Float16)qb0.y;
    qh[5][0] = (_Float16)qb0.z; qh[5][1] = (_Float16)qb0.w;
    qh[6][0] = (_Float16)qb1.x; qh[6][1] = (_Float16)qb1.y;
    qh[7][0] = (_Float16)qb1.z; qh[7][1] = (_Float16)qb1.w;

    float smax = -INFINITY, ssum = 0.0f;
    #pragma unroll
    for (int s = 0; s < 5; ++s) {
        float p = 0.f;
        p = FDOT2(qh[0], as_h2(kv[s][0].x), p);
        p = FDOT2(qh[1], as_h2(kv[s][0].y), p);
        p = FDOT2(qh[2], as_h2(kv[s][0].z), p);
        p = FDOT2(qh[3], as_h2(kv[s][0].w), p);
        p = FDOT2(qh[4], as_h2(kv[s][1].x), p);
        p = FDOT2(qh[5], as_h2(kv[s][1].y), p);
        p = FDOT2(qh[6], as_h2(kv[s][1].z), p);
        p = FDOT2(qh[7], as_h2(kv[s][1].w), p);
        p += __shfl_xor(p, 1);
        p += __shfl_xor(p, 2);
        p += __shfl_xor(p, 4);
        smax = fmaxf(smax, p);
        ssum += p;
    }
    #pragma unroll
    for (int o = 8; o < 64; o <<= 1) {
        smax = fmaxf(smax, __shfl_xor(smax, o));
        ssum += __shfl_xor(ssum, o);
    }
    if (lane == 0) M[(size_t)bh * L_ + q] = smax - ssum * (1.0f / L_);
}

// ---------------- k1 (fp32 fallback, incl. vpartial) -------------------------
__global__ __launch_bounds__(256) void k1_sample_f32(const float* __restrict__ Q,
                                                     const float* __restrict__ K,
                                                     const float* __restrict__ V,
                                                     const int* __restrict__ idx,
                                                     float* __restrict__ M,
                                                     float* __restrict__ vpart) {
    const int bid = blockIdx.x;
    const int t   = threadIdx.x;
    if (bid < 1024) {
        __shared__ float red[256];
        const int vbid = bid;
        const int bh  = vbid >> 5;
        const int lc  = vbid & (VCH_ - 1);
        const int h   = bh & 15, b = bh >> 4;
        const int d   = t & (D_ - 1);
        const int sub = t >> 7;
        float acc = 0.0f;
        const int l0 = lc * (L_ / VCH_);
        for (int l = l0 + sub; l < l0 + L_ / VCH_; l += 2)
            acc += V[((size_t)(b * L_ + l) * H_ + h) * D_ + d];
        red[t] = acc;
        __syncthreads();
        if (t < D_) vpart[(size_t)vbid * D_ + t] = red[t] + red[t + 128];
        return;
    }
    const int sb   = bid - 1024;
    const int xcd  = sb & 7;
    const int li   = sb >> 3;
    const int bh   = (xcd << 2) + (li >> 9);
    const int rb   = li & 511;
    const int wave = t >> 6, lane = t & 63;
    const int q    = rb * 4 + wave;
    const int h    = bh & 15, b = bh >> 4;
    const int g    = lane >> 3, sub = lane & 7;

    const float4* Q4 = (const float4*)Q;
    const float4* K4 = (const float4*)K;
    const size_t rowQ = ((size_t)(b * L_ + q) * H_ + h) * 32;
    const size_t kbase = ((size_t)b * L_ * H_ + h) * 32 + sub;
    const int* ip = idx + q * S_;
    int kidx[5];
    #pragma unroll
    for (int s = 0; s < 5; ++s) kidx[s] = ip[s * 8 + g];
    const float4 qv0 = Q4[rowQ + 0 + sub];
    const float4 qv1 = Q4[rowQ + 8 + sub];
    const float4 qv2 = Q4[rowQ + 16 + sub];
    const float4 qv3 = Q4[rowQ + 24 + sub];
    float4 kv[5][4];
    #pragma unroll
    for (int s = 0; s < 5; ++s) {
        const float4* kb = K4 + kbase + (size_t)kidx[s] * (H_ * 32);
        kv[s][0] = kb[0]; kv[s][1] = kb[8]; kv[s][2] = kb[16]; kv[s][3] = kb[24];
    }
    __builtin_amdgcn_sched_barrier(0);
    float smax = -INFINITY, ssum = 0.0f;
    #pragma unroll
    for (int s = 0; s < 5; ++s) {
        float p = qv0.x * kv[s][0].x + qv0.y * kv[s][0].y + qv0.z * kv[s][0].z + qv0.w * kv[s][0].w
                + qv1.x * kv[s][1].x + qv1.y * kv[s][1].y + qv1.z * kv[s][1].z + qv1.w * kv[s][1].w
                + qv2.x * kv[s][2].x + qv2.y * kv[s][2].y + qv2.z * kv[s][2].z + qv2.w * kv[s][2].w
                + qv3.x * kv[s][3].x + qv3.y * kv[s][3].y + qv3.z * kv[s][3].z + qv3.w * kv[s][3].w;
        p += __shfl_xor(p, 1);
        p += __shfl_xor(p, 2);
        p += __shfl_xor(p, 4);
        smax = fmaxf(smax, p);
        ssum += p;
    }
    #pragma unroll
    for (int o = 8; o < 64; o <<= 1) {
        smax = fmaxf(smax, __shfl_xor(smax, o));
        ssum += __shfl_xor(ssum, o);
    }
    if (lane == 0) M[(size_t)bh * L_ + q] = smax - ssum * (1.0f / L_);
}

// ---------------- k2: radix-T40 + exact refine + select + fill ---------------
__global__ __launch_bounds__(1024) void k2_rank_refine_fill(const float* __restrict__ Mws,
                                                            const float* __restrict__ Q,
                                                            const float* __restrict__ K,
                                                            const int* __restrict__ idx,
                                                            const float* __restrict__ vpart,
                                                            int* __restrict__ topk,
                                                            float* __restrict__ out,
                                                            float delta) {
    const int bid = blockIdx.x, t = threadIdx.x;
    if (bid < 32) {
        __shared__ unsigned int ue[L_];
        __shared__ int hist[256], sscan[256];
        __shared__ int sh_chosen, sh_need, sh_nc;
        __shared__ int clist[CAND_];
        __shared__ float cMx[CAND_];
        __shared__ unsigned int cmaxe[CAND_];
        __shared__ float csum[CAND_];
        const int bh = bid, h = bh & 15, b = bh >> 4;
        const float* Mrow = Mws + (size_t)bh * L_;
        for (int i = t; i < L_; i += 1024) ue[i] = encf(Mrow[i]);
        if (t == 0) sh_nc = 0;
        __syncthreads();

        unsigned int prefix = 0; int need = NTOP_;
        for (int l = 3; l >= 0; --l) {
            if (t < 256) hist[t] = 0;
            __syncthreads();
            for (int i = t; i < L_; i += 1024) {
                const unsigned int u = ue[i];
                const bool match = (l == 3) || ((u >> (8 * (l + 1))) == prefix);
                if (match) atomicAdd(&hist[(u >> (8 * l)) & 255], 1);
            }
            __syncthreads();
            if (t < 256) sscan[t] = hist[t];
            __syncthreads();
            for (int off = 1; off < 256; off <<= 1) {
                int v = 0;
                if (t < 256 && t + off < 256) v = sscan[t + off];
                __syncthreads();
                if (t < 256) sscan[t] += v;
                __syncthreads();
            }
            if (t < 256) {
                const int above = sscan[t] - hist[t];
                if (above < need && need <= above + hist[t]) { sh_chosen = t; sh_need = need - above; }
            }
            __syncthreads();
            prefix = (prefix << 8) | (unsigned int)sh_chosen;
            need = sh_need;
            __syncthreads();
        }
        const unsigned int ethr = encf(decf(prefix) - delta);
        for (int i = t; i < L_; i += 1024) {
            if (ue[i] >= ethr) {
                const int p = atomicAdd(&sh_nc, 1);
                if (p < CAND_) clist[p] = i;
            }
        }
        __syncthreads();
        const int nc = min(sh_nc, CAND_);
        for (int i = t; i < CAND_; i += 1024) { cmaxe[i] = 0x007FFFFFu; csum[i] = 0.f; }
        __syncthreads();

        const float4* Q4 = (const float4*)Q;
        const float4* K4 = (const float4*)K;
        const int grp = t >> 3, sub = t & 7;     // 128 groups
        for (int task = grp; task < nc * S_; task += 128) {
            const int ci = task / S_;
            const int s  = task - ci * S_;
            const int qq = clist[ci];
            const int ki = idx[qq * S_ + s];
            const float4* Kr = K4 + ((size_t)(b * L_ + ki) * H_ + h) * 32;
            const float4* Qr = Q4 + ((size_t)(b * L_ + qq) * H_ + h) * 32;
            float p = 0.f;
            #pragma unroll
            for (int qt2 = 0; qt2 < 4; ++qt2) {
                const float4 kv = Kr[qt2 * 8 + sub];
                const float4 qv = Qr[qt2 * 8 + sub];
                p += qv.x * kv.x + qv.y * kv.y + qv.z * kv.z + qv.w * kv.w;
            }
            p += __shfl_xor(p, 1);
            p += __shfl_xor(p, 2);
            p += __shfl_xor(p, 4);
            if (sub == 0) {
                atomicMax(&cmaxe[ci], encf(p));
                atomicAdd(&csum[ci], p);
            }
        }
        __syncthreads();
        if (t < nc) cMx[t] = decf(cmaxe[t]) - csum[t] * (1.0f / L_);
        __syncthreads();
        if (t < nc) {
            const float mi = cMx[t]; const int qi = clist[t];
            int rk = 0;
            for (int j = 0; j < nc; ++j) {
                const float mj = cMx[j];
                rk += (mj > mi) || (mj == mi && clist[j] < qi);
            }
            if (rk < NTOP_) topk[bh * NTOP_ + rk] = qi;
        }
    } else {
        __shared__ float red[1024];
        __shared__ float vmf[128];
        const int fb = bid - 32;              // 0..511
        const int bh = fb >> 4, sl = fb & 15; // 16 slices of 128 rows
        const int h = bh & 15, b = bh >> 4;
        const int d = t & 127, grp = t >> 7;
        float s = 0.f;
        #pragma unroll
        for (int c = grp * 4; c < grp * 4 + 4; ++c)
            s += vpart[(size_t)(bh * VCH_ + c) * D_ + d];
        red[t] = s;
        __syncthreads();
        if (t < 512) red[t] += red[t + 512];
        __syncthreads();
        if (t < 256) red[t] += red[t + 256];
        __syncthreads();
        if (t < 128) vmf[t] = (red[t] + red[t + 128]) * (1.0f / L_);
        __syncthreads();
        const float4 vm4 = *(const float4*)&vmf[(t & 31) * 4];
        float4* out4 = (float4*)out;
        const int q0 = sl * 128;
        #pragma unroll
        for (int k = 0; k < 4; ++k) {
            const int j = k * 1024 + t;
            const int r = j >> 5, c = j & 31;
            out4[((size_t)(b * L_ + q0 + r) * H_ + h) * 32 + c] = vm4;
        }
    }
}

// ---------------- K3: register-tiled scores + softmax + PV -------------------
__global__ __launch_bounds__(256) void k_scorepv(const float* __restrict__ Q,
                                                 const float* __restrict__ K,
                                                 const float* __restrict__ V,
                                                 const int* __restrict__ topk,
                                                 float* __restrict__ pmax,
                                                 float* __restrict__ psum,
                                                 float* __restrict__ pout) {
    __shared__ float Qs[20 * 132];
    __shared__ float S[20 * 260];
    __shared__ float mrow[20];
    __shared__ int   tq[20];
    const int bid = blockIdx.x;
    const int xcd = bid & 7;
    const int loc = bid >> 3;
    const int bh  = (xcd << 2) + (loc >> 4);
    const int sub16 = loc & 15;
    const int kc  = sub16 >> 1;
    const int uh  = sub16 & 1;
    const int h   = bh & 15, b = bh >> 4;
    const int t   = threadIdx.x;

    if (t < 20) tq[t] = topk[bh * NTOP_ + uh * 20 + t];
    __syncthreads();

    {
        const float4* Q4 = (const float4*)Q;
        #pragma unroll
        for (int it = 0; it < 3; ++it) {
            const int i = it * 256 + t;
            if (i < 640) {
                const int u = i >> 5, dc = i & 31;
                *(float4*)&Qs[u * 132 + dc * 4] =
                    Q4[((size_t)(b * L_ + tq[u]) * H_ + h) * 32 + dc];
            }
        }
    }
    __syncthreads();

    {
        const int kq4 = t >> 2, ug = t & 3;
        float acc[4][5];
        #pragma unroll
        for (int j = 0; j < 4; ++j)
            #pragma unroll
            for (int uu = 0; uu < 5; ++uu) acc[j][uu] = 0.f;
        const float4* Kb = (const float4*)K +
            ((size_t)(b * L_ + kc * CHK_ + kq4 * 4) * H_ + h) * 32;
        for (int dc = 0; dc < 32; ++dc) {
            float4 qv[5];
            #pragma unroll
            for (int uu = 0; uu < 5; ++uu)
                qv[uu] = *(const float4*)&Qs[(ug * 5 + uu) * 132 + dc * 4];
            #pragma unroll
            for (int j = 0; j < 4; ++j) {
                const float4 kv = Kb[(size_t)j * (H_ * 32) + dc];
                #pragma unroll
                for (int uu = 0; uu < 5; ++uu)
                    acc[j][uu] += qv[uu].x * kv.x + qv[uu].y * kv.y
                                + qv[uu].z * kv.z + qv[uu].w * kv.w;
            }
        }
        #pragma unroll
        for (int j = 0; j < 4; ++j)
            #pragma unroll
            for (int uu = 0; uu < 5; ++uu)
                S[(ug * 5 + uu) * 260 + kq4 * 4 + j] = acc[j][uu] * SCALE_;
    }
    __syncthreads();

    {
        const int w = t >> 6, lane = t & 63;
        #pragma unroll
        for (int uu = 0; uu < 5; ++uu) {
            const int u = w * 5 + uu;
            const float* Sr = S + u * 260;
            float v = fmaxf(fmaxf(Sr[lane], Sr[lane + 64]),
                            fmaxf(Sr[lane + 128], Sr[lane + 192]));
            #pragma unroll
            for (int o = 1; o < 64; o <<= 1) v = fmaxf(v, __shfl_xor(v, o, 64));
            if (lane == 0) mrow[u] = v;
        }
    }
    __syncthreads();

    #pragma unroll
    for (int u = 0; u < 20; ++u) S[u * 260 + t] = __expf(S[u * 260 + t] - mrow[u]);
    __syncthreads();

    {
        const int w = t >> 6, lane = t & 63;
        #pragma unroll
        for (int uu = 0; uu < 5; ++uu) {
            const int u = w * 5 + uu;
            const float* Sr = S + u * 260;
            float v = Sr[lane] + Sr[lane + 64] + Sr[lane + 128] + Sr[lane + 192];
            #pragma unroll
            for (int o = 1; o < 64; o <<= 1) v += __shfl_xor(v, o, 64);
            if (lane == 0) {
                psum[(bh * NCH_ + kc) * NTOP_ + uh * 20 + u] = v;
                pmax[(bh * NCH_ + kc) * NTOP_ + uh * 20 + u] = mrow[u];
            }
        }
    }

    {
        const int g = t >> 6, d2 = t & 63;
        const int u0 = g * 5;
        float accA[5], accB[5];
        #pragma unroll
        for (int uu = 0; uu < 5; ++uu) { accA[uu] = 0.f; accB[uu] = 0.f; }
        const float2* Vb = (const float2*)(V + ((size_t)(b * L_ + kc * CHK_) * H_ + h) * D_) + d2;
        for (int kq = 0; kq < CHK_ / 4; ++kq) {
            float2 v0 = Vb[(size_t)(kq * 4 + 0) * (H_ * D_ / 2)];
            float2 v1 = Vb[(size_t)(kq * 4 + 1) * (H_ * D_ / 2)];
            float2 v2 = Vb[(size_t)(kq * 4 + 2) * (H_ * D_ / 2)];
            float2 v3 = Vb[(size_t)(kq * 4 + 3) * (H_ * D_ / 2)];
            #pragma unroll
            for (int uu = 0; uu < 5; ++uu) {
                const float4 p = *(const float4*)&S[(u0 + uu) * 260 + kq * 4];
                accA[uu] += p.x * v0.x + p.y * v1.x + p.z * v2.x + p.w * v3.x;
                accB[uu] += p.x * v0.y + p.y * v1.y + p.z * v2.y + p.w * v3.y;
            }
        }
        float* pb = pout + (((size_t)(bh * NCH_ + kc)) * NTOP_ + uh * 20 + u0) * D_ + d2 * 2;
        #pragma unroll
        for (int uu = 0; uu < 5; ++uu)
            *(float2*)&pb[(size_t)uu * D_] = make_float2(accA[uu], accB[uu]);
    }
}

// ---------------- K4: combine chunk partials, scatter to out -----------------
__global__ __launch_bounds__(128) void k_comb(const float* __restrict__ pmax,
                                              const float* __restrict__ psum,
                                              const float* __restrict__ pout,
                                              const int* __restrict__ topk,
                                              float* __restrict__ out) {
    const int bid = blockIdx.x;          // bh*40 + u
    const int bh  = bid / NTOP_;
    const int u   = bid - bh * NTOP_;
    const int h   = bh & 15, b = bh >> 4;
    const int t   = threadIdx.x;

    float pm[NCH_];
    float M = -INFINITY;
    #pragma unroll
    for (int c = 0; c < NCH_; ++c) {
        pm[c] = pmax[(bh * NCH_ + c) * NTOP_ + u];
        M = fmaxf(M, pm[c]);
    }
    float ssum = 0.0f, o = 0.0f;
    #pragma unroll
    for (int c = 0; c < NCH_; ++c) {
        const float w = __expf(pm[c] - M);
        ssum += psum[(bh * NCH_ + c) * NTOP_ + u] * w;
        o += pout[((size_t)(bh * NCH_ + c) * NTOP_ + u) * D_ + t] * w;
    }
    const int qi = topk[bh * NTOP_ + u];
    out[((size_t)(b * L_ + qi) * H_ + h) * D_ + t] = o / ssum;
}

extern "C" void kernel_launch(void* const* d_in, const int* in_sizes, int n_in,
                              void* d_out, int out_size, void* d_ws, size_t ws_size,
                              hipStream_t stream) {
    const float* Q  = (const float*)d_in[0];
    const float* K  = (const float*)d_in[1];
    const float* V  = (const float*)d_in[2];
    const int* idx  = (const int*)d_in[3];
    float* out      = (float*)d_out;

    char* ws = (char*)d_ws;
    size_t off = 0;
    float* Mws   = (float*)(ws + off); off += (size_t)65536 * 4;
    float* vpart = (float*)(ws + off); off += (size_t)1024 * 128 * 4;
    int*   topk  = (int*)(ws + off);   off += 1280 * 4;
    float* pmax  = (float*)(ws + off); off += (size_t)256 * 40 * 4;
    float* psum  = (float*)(ws + off); off += (size_t)256 * 40 * 4;
    float* pout  = (float*)(ws + off); off += (size_t)256 * 40 * 128 * 4;
    unsigned int* Kf = (unsigned int*)(ws + off);
    const size_t kf_bytes = (size_t)32 * L_ * D_ * 2;      // 16.8 MB
    const bool use_f16 = (ws_size >= off + kf_bytes);

    if (use_f16) {
        hipLaunchKernelGGL(kpack, dim3(256), dim3(256), 0, stream, K, Kf);
        hipLaunchKernelGGL(k1_sample_f16, dim3(1024 + 16384), dim3(256), 0, stream,
                           Q, (const uint4*)Kf, V, idx, Mws, vpart);
    } else {
        hipLaunchKernelGGL(k1_sample_f32, dim3(1024 + 16384), dim3(256), 0, stream,
                           Q, K, V, idx, Mws, vpart);
    }
    hipLaunchKernelGGL(k2_rank_refine_fill, dim3(32 + 512), dim3(1024), 0, stream,
                       Mws, Q, K, idx, vpart, topk, out, use_f16 ? 0.5f : 0.01f);
    hipLaunchKernelGGL(k_scorepv, dim3(512), dim3(256), 0, stream,
                       Q, K, V, topk, pmax, psum, pout);
    hipLaunchKernelGGL(k_comb, dim3(1280), dim3(128), 0, stream,
                       pmax, psum, pout, topk, out);
}